// Round 5
// baseline (86.003 us; speedup 1.0000x reference)
//
#include <hip/hip_runtime.h>
#include <math.h>

// Problem constants (from reference)
#define N_PROP   1000
#define C_ALL    81
#define N_FG     80
#define TOPK     100
#define CAP      1024        // per-class capacity (>= 1000 rows)
#define IMG_WH   800.0f
#define SCORE_TH 0.05f
#define NMS_TH   0.5f
#define MIN_SZ   1.0f
#define BBOX_CLIP 4.135166556742356f   // log(1000/16)

#define DEC_BLK  320         // 5 waves: 4 rows x 80 classes per block
#define NMS_BLK  256

typedef unsigned long long u64;

// Workspace layout (dense [class][row], no counters, no atomics, no memset):
//   [0)                      float4 box [80][1024]   = 1.25 MB
//   [WS_SCORE_OFF)           float  score[80][1024]  = 320 KB (0.0 = invalid)
// Every slot is written unconditionally each call -> immune to the harness
// poison fill; nothing needs pre-zeroing.
#define WS_SCORE_OFF  (N_FG * CAP * 16)
#define WS_REQUIRED   (WS_SCORE_OFF + (size_t)N_FG * CAP * 4)

// ---------------------------------------------------------------- kernel 1
// 250 blocks x 320 threads. Block b owns rows 4b..4b+3, all 80 fg classes.
// Waves 0-3: softmax stats for row 4b+w (coalesced loads + butterfly shfl).
// Decode: thread t handles (class cc = t/4, row r = t%4). Dense writes:
// score (0 if filtered) + box float4 at [cc][4b+r]; 4 consecutive rows per
// class = 16B/64B chunks -> coalesced-enough streaming stores, zero atomics.
__global__ __launch_bounds__(DEC_BLK) void decode_kernel(
    const float* __restrict__ logits,   // [1000][81]
    const float* __restrict__ boxreg,   // [1000][324]
    const float* __restrict__ prop,     // [1000][4]
    char* __restrict__ ws)
{
    float4* wbox   = (float4*)ws;
    float*  wscore = (float*)(ws + WS_SCORE_OFF);

    __shared__ float2 s_ms[4];          // (rowmax, rowsum) for the 4 rows

    const int b    = blockIdx.x;
    const int tid  = threadIdx.x;
    const int wave = tid >> 6;
    const int lane = tid & 63;

    // ---- stats: wave w handles row 4b+w ---------------------------------
    if (wave < 4) {
        const float* row = logits + (4 * b + wave) * C_ALL;
        float v1 = row[lane];
        float v2 = (lane < C_ALL - 64) ? row[64 + lane] : 0.f;

        float m = (lane < C_ALL - 64) ? fmaxf(v1, v2) : v1;
        #pragma unroll
        for (int off = 32; off >= 1; off >>= 1)
            m = fmaxf(m, __shfl_xor(m, off, 64));

        float s = expf(v1 - m) + ((lane < C_ALL - 64) ? expf(v2 - m) : 0.0f);
        #pragma unroll
        for (int off = 32; off >= 1; off >>= 1)
            s += __shfl_xor(s, off, 64);

        if (lane == 0) s_ms[wave] = make_float2(m, s);
    }
    __syncthreads();

    // ---- decode one (class, row) per thread -----------------------------
    const int cc  = tid >> 2;           // 0..79
    const int r   = tid & 3;            // 0..3
    const int n   = 4 * b + r;
    const int col = cc + 1;

    float2 ms = s_ms[r];
    float score = expf(logits[n * C_ALL + col] - ms.x) / ms.y;

    float4 p = *(const float4*)(prop + n * 4);   // 4 rows, L1-broadcast
    float w  = p.z - p.x;
    float h  = p.w - p.y;
    float pcx0 = p.x + 0.5f * w;
    float pcy0 = p.y + 0.5f * h;

    float4 d = *(const float4*)(boxreg + n * (C_ALL * 4) + col * 4);
    float dx = d.x / 10.0f;
    float dy = d.y / 10.0f;
    float dw = fminf(d.z / 5.0f, BBOX_CLIP);
    float dh = fminf(d.w / 5.0f, BBOX_CLIP);

    float pcx = dx * w + pcx0;
    float pcy = dy * h + pcy0;
    float pw  = expf(dw) * w;
    float ph  = expf(dh) * h;

    float x1 = fminf(fmaxf(pcx - 0.5f * pw, 0.0f), IMG_WH);
    float y1 = fminf(fmaxf(pcy - 0.5f * ph, 0.0f), IMG_WH);
    float x2 = fminf(fmaxf(pcx + 0.5f * pw, 0.0f), IMG_WH);
    float y2 = fminf(fmaxf(pcy + 0.5f * ph, 0.0f), IMG_WH);

    float bw = x2 - x1;
    float bh = y2 - y1;
    bool ok = (score >= SCORE_TH) && (bw >= MIN_SZ) && (bh >= MIN_SZ);

    int base = cc * CAP + n;
    wbox[base]   = make_float4(x1, y1, x2, y2);
    wscore[base] = ok ? score : 0.0f;           // 0 = invalid sentinel
}

// ---------------------------------------------------------------- kernel 2
// One block per class: coalesced dense read -> wave-ballot compact into LDS
// (order-independent: keys (score,1023-n) are unique) -> rank sort ->
// NMS (wave-resident V<=64, bit-matrix V<=256, barrier fallback V>256).
__global__ __launch_bounds__(NMS_BLK) void nms_kernel(
    const char* __restrict__ ws,
    float* __restrict__ out)            // 56000 floats
{
    const float4* wbox   = (const float4*)ws;
    const float*  wscore = (const float*)(ws + WS_SCORE_OFF);

    __shared__ u64   s_key[CAP];                    // compacted (unsorted)
    __shared__ float cx1[CAP], cy1[CAP], cx2[CAP], cy2[CAP], car[CAP];
    __shared__ u64   s_skey[CAP];                   // sorted
    __shared__ float sx1[CAP], sy1[CAP], sx2[CAP], sy2[CAP], sar[CAP];
    __shared__ u64   s_mask[256 * 4];
    __shared__ u64   s_keep[4];
    __shared__ unsigned char s_rem[CAP];
    __shared__ int   s_cnt, s_emit;

    const int c    = blockIdx.x;
    const int tid  = threadIdx.x;
    const int lane = tid & 63;
    const int col  = c + 1;

    const int OFF_SCORES = N_FG * TOPK * 4;          // 32000
    const int OFF_LABELS = OFF_SCORES + N_FG * TOPK; // 40000
    const int OFF_VALID  = OFF_LABELS + N_FG * TOPK; // 48000

    // Zero this class's output slice (harness poisons d_out every call).
    if (tid < 175) {
        float4 z = make_float4(0.f, 0.f, 0.f, 0.f);
        if (tid < 100)      ((float4*)(out + c * TOPK * 4))[tid] = z;
        else if (tid < 125) ((float4*)(out + OFF_SCORES + c * TOPK))[tid - 100] = z;
        else if (tid < 150) ((float4*)(out + OFF_LABELS + c * TOPK))[tid - 125] = z;
        else                ((float4*)(out + OFF_VALID  + c * TOPK))[tid - 150] = z;
    }
    if (tid == 0) { s_cnt = 0; s_emit = 0; }
    __syncthreads();

    // ---- coalesced load + wave-ballot compaction ------------------------
    for (int t0 = 0; t0 < N_PROP; t0 += NMS_BLK) {
        int t = t0 + tid;                       // t == original row n
        float sc = (t < N_PROP) ? wscore[c * CAP + t] : 0.0f;
        float4 bx = (t < N_PROP) ? wbox[c * CAP + t]
                                 : make_float4(0.f, 0.f, 0.f, 0.f);
        bool valid = sc > 0.0f;
        u64 bal = __ballot(valid);
        int pop = __popcll(bal);
        int wbase = 0;
        if (lane == 0) wbase = atomicAdd(&s_cnt, pop);
        wbase = __shfl(wbase, 0, 64);
        if (valid) {
            int slot = wbase + __popcll(bal & ((1ull << lane) - 1ull));
            // key: (score bits | 1023-n) -> descending-u64
            // == (score desc, original index asc); unique per class.
            s_key[slot] = ((u64)__float_as_uint(sc) << 10) | (u64)(1023 - t);
            cx1[slot] = bx.x; cy1[slot] = bx.y;
            cx2[slot] = bx.z; cy2[slot] = bx.w;
            car[slot] = (bx.z - bx.x) * (bx.w - bx.y);
        }
    }
    __syncthreads();

    const int V = s_cnt;
    if (V == 0) return;                 // outputs already zeroed

    // ---- rank sort (keys unique -> ranks unique) ------------------------
    for (int t = tid; t < V; t += NMS_BLK) {
        u64 myk = s_key[t];
        int rank = 0;
        #pragma unroll 4
        for (int j = 0; j < V; ++j) rank += (s_key[j] > myk) ? 1 : 0;
        s_skey[rank] = myk;
        sx1[rank] = cx1[t]; sy1[rank] = cy1[t];
        sx2[rank] = cx2[t]; sy2[rank] = cy2[t];
        sar[rank] = car[t];
    }
    __syncthreads();

    if (V <= 64) {
        // ---- Wave-resident NMS: lane j holds sorted box j ---------------
        if (tid < 64) {
            bool act = lane < V;
            float bx1 = 0.f, by1 = 0.f, bx2 = 0.f, by2 = 0.f, bar = 0.f;
            if (act) {
                bx1 = sx1[lane]; by1 = sy1[lane];
                bx2 = sx2[lane]; by2 = sy2[lane];
                bar = sar[lane];
            }
            u64 myrow = 0;   // suppression row i (held by lane i)
            for (int i = 0; i < V; ++i) {
                float ix1 = __shfl(bx1, i, 64);
                float iy1 = __shfl(by1, i, 64);
                float ix2 = __shfl(bx2, i, 64);
                float iy2 = __shfl(by2, i, 64);
                float iar = __shfl(bar, i, 64);
                float lx = fmaxf(ix1, bx1);
                float ly = fmaxf(iy1, by1);
                float rx = fminf(ix2, bx2);
                float ry = fminf(iy2, by2);
                float iw = fmaxf(rx - lx, 0.0f);
                float ih = fmaxf(ry - ly, 0.0f);
                float inter = iw * ih;
                float iou = inter / (iar + bar - inter + 1e-9f);
                u64 bal = __ballot(act && (iou > NMS_TH));
                if (lane == i) {
                    u64 upper = (i == 63) ? 0ull : ~((1ull << (i + 1)) - 1ull);
                    myrow = bal & upper;
                }
            }
            u64 S = 0, K = 0;
            for (int i = 0; i < V; ++i) {
                if (!((S >> i) & 1ull)) {
                    K |= 1ull << i;
                    S |= __shfl(myrow, i, 64);
                }
            }
            if (act && ((K >> lane) & 1ull)) {
                int rank = __popcll(K & ((1ull << lane) - 1ull));
                float score = __uint_as_float((unsigned int)(s_skey[lane] >> 10));
                out[(c * TOPK + rank) * 4 + 0] = bx1;
                out[(c * TOPK + rank) * 4 + 1] = by1;
                out[(c * TOPK + rank) * 4 + 2] = bx2;
                out[(c * TOPK + rank) * 4 + 3] = by2;
                out[OFF_SCORES + c * TOPK + rank] = score;
                out[OFF_LABELS + c * TOPK + rank] = (float)col;
                out[OFF_VALID  + c * TOPK + rank] = 1.0f;
            }
        }
    } else if (V <= 256) {
        // ---- Bit-matrix NMS (all 4 words written for unconditional
        //      prefetch in the serial scan) -------------------------------
        for (int i = tid; i < V; i += NMS_BLK) {
            float x1i = sx1[i], y1i = sy1[i], x2i = sx2[i], y2i = sy2[i];
            float ai  = sar[i];
            for (int w = 0; w < 4; ++w) {
                u64 mrow = 0;
                int j0 = w << 6;
                int j1 = min(V, j0 + 64);
                for (int j = max(j0, i + 1); j < j1; ++j) {
                    float lx = fmaxf(x1i, sx1[j]);
                    float ly = fmaxf(y1i, sy1[j]);
                    float rx = fminf(x2i, sx2[j]);
                    float ry = fminf(y2i, sy2[j]);
                    float iw = fmaxf(rx - lx, 0.0f);
                    float ih = fmaxf(ry - ly, 0.0f);
                    float inter = iw * ih;
                    float iou = inter / (ai + sar[j] - inter + 1e-9f);
                    if (iou > NMS_TH) mrow |= 1ull << (j - j0);
                }
                s_mask[(i << 2) + w] = mrow;
            }
        }
        __syncthreads();

        if (tid == 0) {
            // Serial greedy scan, depth-2 software pipeline.
            u64 r0 = 0, r1 = 0, r2 = 0, r3 = 0;
            u64 k0 = 0, k1 = 0, k2 = 0, k3 = 0;
            int kept = 0;
            u64 p0 = s_mask[0], p1 = s_mask[1], p2 = s_mask[2], p3 = s_mask[3];
            u64 q0 = 0, q1 = 0, q2 = 0, q3 = 0;
            if (V > 1) {
                const u64* nr = &s_mask[4];
                q0 = nr[0]; q1 = nr[1]; q2 = nr[2]; q3 = nr[3];
            }
            for (int i = 0; i < V; ++i) {
                u64 t0 = 0, t1 = 0, t2 = 0, t3 = 0;
                if (i + 2 < V) {
                    const u64* nr = &s_mask[(i + 2) << 2];
                    t0 = nr[0]; t1 = nr[1]; t2 = nr[2]; t3 = nr[3];
                }
                int w = i >> 6;
                u64 bit = 1ull << (i & 63);
                u64 rw = (w == 0) ? r0 : (w == 1) ? r1 : (w == 2) ? r2 : r3;
                if (!(rw & bit)) {
                    if (w == 0) k0 |= bit; else if (w == 1) k1 |= bit;
                    else if (w == 2) k2 |= bit; else k3 |= bit;
                    if (++kept >= TOPK) break;
                    r0 |= p0; r1 |= p1; r2 |= p2; r3 |= p3;
                }
                p0 = q0; p1 = q1; p2 = q2; p3 = q3;
                q0 = t0; q1 = t1; q2 = t2; q3 = t3;
            }
            s_keep[0] = k0; s_keep[1] = k1; s_keep[2] = k2; s_keep[3] = k3;
        }
        __syncthreads();

        u64 kw0 = s_keep[0], kw1 = s_keep[1], kw2 = s_keep[2], kw3 = s_keep[3];
        for (int t = tid; t < V; t += NMS_BLK) {
            int w = t >> 6;
            u64 kw = (w == 0) ? kw0 : (w == 1) ? kw1 : (w == 2) ? kw2 : kw3;
            if (!((kw >> (t & 63)) & 1ull)) continue;
            int rank = 0;
            if (w > 0) rank += __popcll(kw0);
            if (w > 1) rank += __popcll(kw1);
            if (w > 2) rank += __popcll(kw2);
            rank += __popcll(kw & ((1ull << (t & 63)) - 1ull));
            if (rank < TOPK) {
                float score = __uint_as_float((unsigned int)(s_skey[t] >> 10));
                out[(c * TOPK + rank) * 4 + 0] = sx1[t];
                out[(c * TOPK + rank) * 4 + 1] = sy1[t];
                out[(c * TOPK + rank) * 4 + 2] = sx2[t];
                out[(c * TOPK + rank) * 4 + 3] = sy2[t];
                out[OFF_SCORES + c * TOPK + rank] = score;
                out[OFF_LABELS + c * TOPK + rank] = (float)col;
                out[OFF_VALID  + c * TOPK + rank] = 1.0f;
            }
        }
    } else {
        // ---- Fallback (V > 256): barrier greedy -------------------------
        for (int t = tid; t < V; t += NMS_BLK) s_rem[t] = 0;
        __syncthreads();
        for (int i = 0; i < V; ++i) {
            if (s_rem[i]) continue;
            if (tid == 0) {
                int k = s_emit;
                if (k < TOPK) {
                    float score = __uint_as_float((unsigned int)(s_skey[i] >> 10));
                    out[(c * TOPK + k) * 4 + 0] = sx1[i];
                    out[(c * TOPK + k) * 4 + 1] = sy1[i];
                    out[(c * TOPK + k) * 4 + 2] = sx2[i];
                    out[(c * TOPK + k) * 4 + 3] = sy2[i];
                    out[OFF_SCORES + c * TOPK + k] = score;
                    out[OFF_LABELS + c * TOPK + k] = (float)col;
                    out[OFF_VALID  + c * TOPK + k] = 1.0f;
                }
                s_emit = k + 1;
            }
            float x1i = sx1[i], y1i = sy1[i], x2i = sx2[i], y2i = sy2[i];
            float ai  = sar[i];
            for (int jj = i + 1 + tid; jj < V; jj += NMS_BLK) {
                if (s_rem[jj]) continue;
                float lx = fmaxf(x1i, sx1[jj]);
                float ly = fmaxf(y1i, sy1[jj]);
                float rx = fminf(x2i, sx2[jj]);
                float ry = fminf(y2i, sy2[jj]);
                float iw = fmaxf(rx - lx, 0.0f);
                float ih = fmaxf(ry - ly, 0.0f);
                float inter = iw * ih;
                float iou = inter / (ai + sar[jj] - inter + 1e-9f);
                if (iou > NMS_TH) s_rem[jj] = 1;
            }
            __syncthreads();
            if (s_emit >= TOPK) break;
        }
    }
}

// ---------------------------------------------------------------- fallback
// Round-3 fused single-kernel path (harness-verified), used only if the
// workspace is too small for the split pipeline.
__global__ __launch_bounds__(512) void roihead_fused_kernel(
    const float* __restrict__ logits,
    const float* __restrict__ boxreg,
    const float* __restrict__ prop,
    float* __restrict__ out)
{
    __shared__ float2 s_stats[N_PROP];
    __shared__ u64   s_key[CAP];
    __shared__ float cx1[CAP], cy1[CAP], cx2[CAP], cy2[CAP], car[CAP];
    __shared__ u64   s_skey[CAP];
    __shared__ float sx1[CAP], sy1[CAP], sx2[CAP], sy2[CAP], sar[CAP];
    __shared__ u64   s_mask[256 * 4];
    __shared__ u64   s_keep[4];
    __shared__ unsigned char s_rem[CAP];
    __shared__ int   s_cnt, s_emit;

    const int c   = blockIdx.x;
    const int tid = threadIdx.x;
    const int col = c + 1;

    const int OFF_SCORES = N_FG * TOPK * 4;
    const int OFF_LABELS = OFF_SCORES + N_FG * TOPK;
    const int OFF_VALID  = OFF_LABELS + N_FG * TOPK;

    if (tid < 175) {
        float4 z = make_float4(0.f, 0.f, 0.f, 0.f);
        if (tid < 100)      ((float4*)(out + c * TOPK * 4))[tid] = z;
        else if (tid < 125) ((float4*)(out + OFF_SCORES + c * TOPK))[tid - 100] = z;
        else if (tid < 150) ((float4*)(out + OFF_LABELS + c * TOPK))[tid - 125] = z;
        else                ((float4*)(out + OFF_VALID  + c * TOPK))[tid - 150] = z;
    }
    if (tid == 0) { s_cnt = 0; s_emit = 0; }

    for (int n = tid; n < N_PROP; n += 512) {
        const float* row = logits + n * C_ALL;
        float m = -1e30f;
        for (int j = 0; j < C_ALL; ++j) m = fmaxf(m, row[j]);
        float s = 0.0f;
        for (int j = 0; j < C_ALL; ++j) s += expf(row[j] - m);
        s_stats[n] = make_float2(m, s);
    }
    __syncthreads();

    for (int n = tid; n < N_PROP; n += 512) {
        float2 ms = s_stats[n];
        float score = expf(logits[n * C_ALL + col] - ms.x) / ms.y;
        float4 p = *(const float4*)(prop + n * 4);
        float w  = p.z - p.x;
        float h  = p.w - p.y;
        float pcx0 = p.x + 0.5f * w;
        float pcy0 = p.y + 0.5f * h;
        float4 d = *(const float4*)(boxreg + n * (C_ALL * 4) + col * 4);
        float dx = d.x / 10.0f;
        float dy = d.y / 10.0f;
        float dw = fminf(d.z / 5.0f, BBOX_CLIP);
        float dh = fminf(d.w / 5.0f, BBOX_CLIP);
        float pcx = dx * w + pcx0;
        float pcy = dy * h + pcy0;
        float pw  = expf(dw) * w;
        float ph  = expf(dh) * h;
        float x1 = fminf(fmaxf(pcx - 0.5f * pw, 0.0f), IMG_WH);
        float y1 = fminf(fmaxf(pcy - 0.5f * ph, 0.0f), IMG_WH);
        float x2 = fminf(fmaxf(pcx + 0.5f * pw, 0.0f), IMG_WH);
        float y2 = fminf(fmaxf(pcy + 0.5f * ph, 0.0f), IMG_WH);
        float bw = x2 - x1;
        float bh = y2 - y1;
        if (score >= SCORE_TH && bw >= MIN_SZ && bh >= MIN_SZ) {
            int slot = atomicAdd(&s_cnt, 1);
            unsigned int fb = __float_as_uint(score);
            s_key[slot] = ((u64)fb << 20) | ((u64)(1023 - n) << 10) | (u64)slot;
            cx1[slot] = x1; cy1[slot] = y1; cx2[slot] = x2; cy2[slot] = y2;
            car[slot] = bw * bh;
        }
    }
    __syncthreads();

    const int V = s_cnt;
    if (V == 0) return;

    for (int t = tid; t < V; t += 512) {
        u64 myk = s_key[t];
        int rank = 0;
        for (int j = 0; j < V; ++j) rank += (s_key[j] > myk) ? 1 : 0;
        s_skey[rank] = myk;
        sx1[rank] = cx1[t]; sy1[rank] = cy1[t];
        sx2[rank] = cx2[t]; sy2[rank] = cy2[t];
        sar[rank] = car[t];
    }
    __syncthreads();

    if (V <= 64) {
        if (tid < 64) {
            const int lane = tid;
            bool act = lane < V;
            float bx1 = 0.f, by1 = 0.f, bx2 = 0.f, by2 = 0.f, bar = 0.f;
            if (act) {
                bx1 = sx1[lane]; by1 = sy1[lane];
                bx2 = sx2[lane]; by2 = sy2[lane];
                bar = sar[lane];
            }
            u64 myrow = 0;
            for (int i = 0; i < V; ++i) {
                float ix1 = __shfl(bx1, i, 64);
                float iy1 = __shfl(by1, i, 64);
                float ix2 = __shfl(bx2, i, 64);
                float iy2 = __shfl(by2, i, 64);
                float iar = __shfl(bar, i, 64);
                float lx = fmaxf(ix1, bx1);
                float ly = fmaxf(iy1, by1);
                float rx = fminf(ix2, bx2);
                float ry = fminf(iy2, by2);
                float iw = fmaxf(rx - lx, 0.0f);
                float ih = fmaxf(ry - ly, 0.0f);
                float inter = iw * ih;
                float iou = inter / (iar + bar - inter + 1e-9f);
                u64 bal = __ballot(act && (iou > NMS_TH));
                if (lane == i) {
                    u64 upper = (i == 63) ? 0ull : ~((1ull << (i + 1)) - 1ull);
                    myrow = bal & upper;
                }
            }
            u64 S = 0, K = 0;
            for (int i = 0; i < V; ++i) {
                if (!((S >> i) & 1ull)) {
                    K |= 1ull << i;
                    S |= __shfl(myrow, i, 64);
                }
            }
            if (act && ((K >> lane) & 1ull)) {
                int rank = __popcll(K & ((1ull << lane) - 1ull));
                float score = __uint_as_float((unsigned int)(s_skey[lane] >> 20));
                out[(c * TOPK + rank) * 4 + 0] = bx1;
                out[(c * TOPK + rank) * 4 + 1] = by1;
                out[(c * TOPK + rank) * 4 + 2] = bx2;
                out[(c * TOPK + rank) * 4 + 3] = by2;
                out[OFF_SCORES + c * TOPK + rank] = score;
                out[OFF_LABELS + c * TOPK + rank] = (float)col;
                out[OFF_VALID  + c * TOPK + rank] = 1.0f;
            }
        }
    } else if (V <= 256) {
        for (int i = tid; i < V; i += 512) {
            float x1i = sx1[i], y1i = sy1[i], x2i = sx2[i], y2i = sy2[i];
            float ai  = sar[i];
            for (int w = 0; w < 4; ++w) {
                u64 mrow = 0;
                int j0 = w << 6;
                int j1 = min(V, j0 + 64);
                for (int j = max(j0, i + 1); j < j1; ++j) {
                    float lx = fmaxf(x1i, sx1[j]);
                    float ly = fmaxf(y1i, sy1[j]);
                    float rx = fminf(x2i, sx2[j]);
                    float ry = fminf(y2i, sy2[j]);
                    float iw = fmaxf(rx - lx, 0.0f);
                    float ih = fmaxf(ry - ly, 0.0f);
                    float inter = iw * ih;
                    float iou = inter / (ai + sar[j] - inter + 1e-9f);
                    if (iou > NMS_TH) mrow |= 1ull << (j - j0);
                }
                s_mask[(i << 2) + w] = mrow;
            }
        }
        __syncthreads();
        if (tid == 0) {
            u64 r0 = 0, r1 = 0, r2 = 0, r3 = 0;
            u64 k0 = 0, k1 = 0, k2 = 0, k3 = 0;
            int kept = 0;
            for (int i = 0; i < V; ++i) {
                int w = i >> 6;
                u64 bit = 1ull << (i & 63);
                u64 rw = (w == 0) ? r0 : (w == 1) ? r1 : (w == 2) ? r2 : r3;
                if (rw & bit) continue;
                if (w == 0) k0 |= bit; else if (w == 1) k1 |= bit;
                else if (w == 2) k2 |= bit; else k3 |= bit;
                if (++kept >= TOPK) break;
                const u64* mr = &s_mask[i << 2];
                r0 |= mr[0]; r1 |= mr[1]; r2 |= mr[2]; r3 |= mr[3];
            }
            s_keep[0] = k0; s_keep[1] = k1; s_keep[2] = k2; s_keep[3] = k3;
        }
        __syncthreads();
        u64 kw0 = s_keep[0], kw1 = s_keep[1], kw2 = s_keep[2], kw3 = s_keep[3];
        for (int t = tid; t < V; t += 512) {
            int w = t >> 6;
            u64 kw = (w == 0) ? kw0 : (w == 1) ? kw1 : (w == 2) ? kw2 : kw3;
            if (!((kw >> (t & 63)) & 1ull)) continue;
            int rank = 0;
            if (w > 0) rank += __popcll(kw0);
            if (w > 1) rank += __popcll(kw1);
            if (w > 2) rank += __popcll(kw2);
            rank += __popcll(kw & ((1ull << (t & 63)) - 1ull));
            if (rank < TOPK) {
                float score = __uint_as_float((unsigned int)(s_skey[t] >> 20));
                out[(c * TOPK + rank) * 4 + 0] = sx1[t];
                out[(c * TOPK + rank) * 4 + 1] = sy1[t];
                out[(c * TOPK + rank) * 4 + 2] = sx2[t];
                out[(c * TOPK + rank) * 4 + 3] = sy2[t];
                out[OFF_SCORES + c * TOPK + rank] = score;
                out[OFF_LABELS + c * TOPK + rank] = (float)col;
                out[OFF_VALID  + c * TOPK + rank] = 1.0f;
            }
        }
    } else {
        for (int t = tid; t < V; t += 512) s_rem[t] = 0;
        __syncthreads();
        for (int i = 0; i < V; ++i) {
            if (s_rem[i]) continue;
            if (tid == 0) {
                int k = s_emit;
                if (k < TOPK) {
                    float score = __uint_as_float((unsigned int)(s_skey[i] >> 20));
                    out[(c * TOPK + k) * 4 + 0] = sx1[i];
                    out[(c * TOPK + k) * 4 + 1] = sy1[i];
                    out[(c * TOPK + k) * 4 + 2] = sx2[i];
                    out[(c * TOPK + k) * 4 + 3] = sy2[i];
                    out[OFF_SCORES + c * TOPK + k] = score;
                    out[OFF_LABELS + c * TOPK + k] = (float)col;
                    out[OFF_VALID  + c * TOPK + k] = 1.0f;
                }
                s_emit = k + 1;
            }
            float x1i = sx1[i], y1i = sy1[i], x2i = sx2[i], y2i = sy2[i];
            float ai  = sar[i];
            for (int jj = i + 1 + tid; jj < V; jj += 512) {
                if (s_rem[jj]) continue;
                float lx = fmaxf(x1i, sx1[jj]);
                float ly = fmaxf(y1i, sy1[jj]);
                float rx = fminf(x2i, sx2[jj]);
                float ry = fminf(y2i, sy2[jj]);
                float iw = fmaxf(rx - lx, 0.0f);
                float ih = fmaxf(ry - ly, 0.0f);
                float inter = iw * ih;
                float iou = inter / (ai + sar[jj] - inter + 1e-9f);
                if (iou > NMS_TH) s_rem[jj] = 1;
            }
            __syncthreads();
            if (s_emit >= TOPK) break;
        }
    }
}

extern "C" void kernel_launch(void* const* d_in, const int* in_sizes, int n_in,
                              void* d_out, int out_size, void* d_ws, size_t ws_size,
                              hipStream_t stream) {
    const float* class_logit = (const float*)d_in[0];   // [1000][81]
    const float* box_reg     = (const float*)d_in[1];   // [1000][324]
    const float* proposal    = (const float*)d_in[2];   // [1000][4]
    float* out = (float*)d_out;                         // 56000 floats

    if (ws_size >= WS_REQUIRED) {
        decode_kernel<<<N_PROP / 4, DEC_BLK, 0, stream>>>(
            class_logit, box_reg, proposal, (char*)d_ws);
        nms_kernel<<<N_FG, NMS_BLK, 0, stream>>>((const char*)d_ws, out);
    } else {
        roihead_fused_kernel<<<N_FG, 512, 0, stream>>>(
            class_logit, box_reg, proposal, out);
    }
}

// Round 6
// 83.622 us; speedup vs baseline: 1.0285x; 1.0285x over previous
//
#include <hip/hip_runtime.h>
#include <math.h>

// Problem constants (from reference)
#define N_PROP   1000
#define C_ALL    81
#define N_FG     80
#define TOPK     100
#define CAP      1024
#define IMG_WH   800.0f
#define SCORE_TH 0.05f
#define NMS_TH   0.5f
#define MIN_SZ   1.0f
#define BBOX_CLIP 4.135166556742356f   // log(1000/16)

typedef unsigned long long u64;

// Workspace: float2 stats[1000] = 8 KB. Written every call (no stale-data
// hazard from the harness poison fill).
#define WS_REQUIRED (sizeof(float2) * N_PROP)

// ---------------------------------------------------------------- kernel 1
// Softmax stats, one wave per row (verified round-0 pattern).
__global__ __launch_bounds__(256) void stats_kernel(
    const float* __restrict__ logits,   // [1000][81]
    float2* __restrict__ stats)         // [1000] (rowmax, rowsum)
{
    const int wave = threadIdx.x >> 6;
    const int lane = threadIdx.x & 63;
    const int n = blockIdx.x * 4 + wave;
    if (n >= N_PROP) return;
    const float* row = logits + n * C_ALL;

    float v1 = row[lane];
    float v2 = (lane < C_ALL - 64) ? row[64 + lane] : 0.f;

    float m = (lane < C_ALL - 64) ? fmaxf(v1, v2) : v1;
    #pragma unroll
    for (int off = 32; off >= 1; off >>= 1)
        m = fmaxf(m, __shfl_xor(m, off, 64));

    float s = expf(v1 - m) + ((lane < C_ALL - 64) ? expf(v2 - m) : 0.0f);
    #pragma unroll
    for (int off = 32; off >= 1; off >>= 1)
        s += __shfl_xor(s, off, 64);

    if (lane == 0) stats[n] = make_float2(m, s);
}

// ---------------------------------------------------------------- kernel 2
// One block (256 thr) per class:
//   score all 1000 rows from logits directly -> ballot-compact candidates
//   (~55) -> decode ONLY candidates -> rank sort -> NMS -> structured
//   TOPK output write (no separate zeroing pass).
__global__ __launch_bounds__(256) void nms_kernel(
    const float* __restrict__ logits,   // [1000][81]
    const float* __restrict__ boxreg,   // [1000][324]
    const float* __restrict__ prop,     // [1000][4]
    const float2* __restrict__ stats,   // [1000] or nullptr (ws fallback)
    float* __restrict__ out)            // 56000 floats
{
    __shared__ float2 s_ms[N_PROP];                 // 8KB stats
    __shared__ unsigned short s_cn[CAP];            // candidate row ids
    __shared__ float s_csc[CAP];                    // candidate scores
    __shared__ u64   s_key[CAP];                    // compacted (unsorted)
    __shared__ float cx1[CAP], cy1[CAP], cx2[CAP], cy2[CAP], car[CAP];
    __shared__ u64   s_skey[CAP];                   // sorted
    __shared__ float sx1[CAP], sy1[CAP], sx2[CAP], sy2[CAP], sar[CAP];
    __shared__ u64   s_mask[256 * 4];
    __shared__ unsigned char s_rem[CAP];
    __shared__ unsigned short s_src[TOPK];          // rank -> sorted index
    __shared__ int   s_nc, s_cnt, s_emit, s_nk;

    const int c    = blockIdx.x;
    const int tid  = threadIdx.x;
    const int lane = tid & 63;
    const int col  = c + 1;

    const int OFF_SCORES = N_FG * TOPK * 4;          // 32000
    const int OFF_LABELS = OFF_SCORES + N_FG * TOPK; // 40000
    const int OFF_VALID  = OFF_LABELS + N_FG * TOPK; // 48000

    if (tid == 0) { s_nc = 0; s_cnt = 0; s_emit = 0; s_nk = 0; }

    // ---- stats into LDS -------------------------------------------------
    if (stats != nullptr) {
        for (int t = tid; t < N_PROP; t += 256) s_ms[t] = stats[t];
    } else {
        // ws-too-small fallback: per-block stats (round-3 verified math)
        for (int n = tid; n < N_PROP; n += 256) {
            const float* row = logits + n * C_ALL;
            float m = -1e30f;
            for (int j = 0; j < C_ALL; ++j) m = fmaxf(m, row[j]);
            float s = 0.0f;
            for (int j = 0; j < C_ALL; ++j) s += expf(row[j] - m);
            s_ms[n] = make_float2(m, s);
        }
    }
    __syncthreads();

    // ---- phase B: score + threshold + ballot-compact candidates ---------
    #pragma unroll
    for (int k = 0; k < 4; ++k) {
        int n = k * 256 + tid;
        bool v = false; float sc = 0.0f;
        if (n < N_PROP) {
            float2 ms = s_ms[n];
            sc = expf(logits[n * C_ALL + col] - ms.x) / ms.y;
            v = (sc >= SCORE_TH);
        }
        u64 bal = __ballot(v);
        int pop = __popcll(bal);
        int wb = 0;
        if (lane == 0 && pop) wb = atomicAdd(&s_nc, pop);
        wb = __shfl(wb, 0, 64);
        if (v) {
            int slot = wb + __popcll(bal & ((1ull << lane) - 1ull));
            s_cn[slot]  = (unsigned short)n;
            s_csc[slot] = sc;
        }
    }
    __syncthreads();
    const int NC = s_nc;

    // ---- decode ONLY candidates ----------------------------------------
    for (int t = tid; t < NC; t += 256) {
        int n = s_cn[t];
        float sc = s_csc[t];

        float4 p = *(const float4*)(prop + n * 4);
        float w  = p.z - p.x;
        float h  = p.w - p.y;
        float pcx0 = p.x + 0.5f * w;
        float pcy0 = p.y + 0.5f * h;

        float4 d = *(const float4*)(boxreg + n * (C_ALL * 4) + col * 4);
        float dx = d.x / 10.0f;
        float dy = d.y / 10.0f;
        float dw = fminf(d.z / 5.0f, BBOX_CLIP);
        float dh = fminf(d.w / 5.0f, BBOX_CLIP);

        float pcx = dx * w + pcx0;
        float pcy = dy * h + pcy0;
        float pw  = expf(dw) * w;
        float ph  = expf(dh) * h;

        float x1 = fminf(fmaxf(pcx - 0.5f * pw, 0.0f), IMG_WH);
        float y1 = fminf(fmaxf(pcy - 0.5f * ph, 0.0f), IMG_WH);
        float x2 = fminf(fmaxf(pcx + 0.5f * pw, 0.0f), IMG_WH);
        float y2 = fminf(fmaxf(pcy + 0.5f * ph, 0.0f), IMG_WH);

        float bw = x2 - x1;
        float bh = y2 - y1;
        if (bw >= MIN_SZ && bh >= MIN_SZ) {
            int slot = atomicAdd(&s_cnt, 1);
            // key: (score bits | 1023-n) -> descending-u64
            // == (score desc, original index asc); unique per class,
            // so compaction/append order cannot affect results.
            s_key[slot] = ((u64)__float_as_uint(sc) << 10) | (u64)(1023 - n);
            cx1[slot] = x1; cy1[slot] = y1; cx2[slot] = x2; cy2[slot] = y2;
            car[slot] = bw * bh;
        }
    }
    __syncthreads();

    const int V = s_cnt;

    if (V > 0) {
        // ---- rank sort (keys unique -> ranks unique) --------------------
        for (int t = tid; t < V; t += 256) {
            u64 myk = s_key[t];
            int rank = 0;
            #pragma unroll 4
            for (int j = 0; j < V; ++j) rank += (s_key[j] > myk) ? 1 : 0;
            s_skey[rank] = myk;
            sx1[rank] = cx1[t]; sy1[rank] = cy1[t];
            sx2[rank] = cx2[t]; sy2[rank] = cy2[t];
            sar[rank] = car[t];
        }
        __syncthreads();

        if (V <= 64) {
            // ---- wave-resident NMS: lane j holds sorted box j -----------
            if (tid < 64) {
                bool act = lane < V;
                float bx1 = 0.f, by1 = 0.f, bx2 = 0.f, by2 = 0.f, bar = 0.f;
                if (act) {
                    bx1 = sx1[lane]; by1 = sy1[lane];
                    bx2 = sx2[lane]; by2 = sy2[lane];
                    bar = sar[lane];
                }
                u64 myrow = 0;   // suppression row i (held by lane i)
                for (int i = 0; i < V; ++i) {
                    float ix1 = __shfl(bx1, i, 64);
                    float iy1 = __shfl(by1, i, 64);
                    float ix2 = __shfl(bx2, i, 64);
                    float iy2 = __shfl(by2, i, 64);
                    float iar = __shfl(bar, i, 64);
                    float lx = fmaxf(ix1, bx1);
                    float ly = fmaxf(iy1, by1);
                    float rx = fminf(ix2, bx2);
                    float ry = fminf(iy2, by2);
                    float iw = fmaxf(rx - lx, 0.0f);
                    float ih = fmaxf(ry - ly, 0.0f);
                    float inter = iw * ih;
                    float iou = inter / (iar + bar - inter + 1e-9f);
                    u64 bal = __ballot(act && (iou > NMS_TH));
                    if (lane == i) {
                        u64 upper = (i == 63) ? 0ull : ~((1ull << (i + 1)) - 1ull);
                        myrow = bal & upper;
                    }
                }
                u64 S = 0, K = 0;
                for (int i = 0; i < V; ++i) {
                    if (!((S >> i) & 1ull)) {
                        K |= 1ull << i;
                        S |= __shfl(myrow, i, 64);
                    }
                }
                // V <= 64 < TOPK: every kept box emitted; record rank map.
                if (act && ((K >> lane) & 1ull)) {
                    int rank = __popcll(K & ((1ull << lane) - 1ull));
                    s_src[rank] = (unsigned short)lane;
                }
                if (lane == 0) s_nk = __popcll(K);
            }
        } else if (V <= 256) {
            // ---- bit-matrix NMS (all 4 words written so the serial scan
            //      can prefetch unconditionally) ---------------------------
            for (int i = tid; i < V; i += 256) {
                float x1i = sx1[i], y1i = sy1[i], x2i = sx2[i], y2i = sy2[i];
                float ai  = sar[i];
                for (int w = 0; w < 4; ++w) {
                    u64 mrow = 0;
                    int j0 = w << 6;
                    int j1 = min(V, j0 + 64);
                    for (int j = max(j0, i + 1); j < j1; ++j) {
                        float lx = fmaxf(x1i, sx1[j]);
                        float ly = fmaxf(y1i, sy1[j]);
                        float rx = fminf(x2i, sx2[j]);
                        float ry = fminf(y2i, sy2[j]);
                        float iw = fmaxf(rx - lx, 0.0f);
                        float ih = fmaxf(ry - ly, 0.0f);
                        float inter = iw * ih;
                        float iou = inter / (ai + sar[j] - inter + 1e-9f);
                        if (iou > NMS_TH) mrow |= 1ull << (j - j0);
                    }
                    s_mask[(i << 2) + w] = mrow;
                }
            }
            __syncthreads();

            if (tid == 0) {
                // Serial greedy scan, depth-2 software pipeline; record
                // s_src[rank] directly (replaces the old emit pass).
                u64 r0 = 0, r1 = 0, r2 = 0, r3 = 0;
                int kept = 0;
                u64 p0 = s_mask[0], p1 = s_mask[1], p2 = s_mask[2], p3 = s_mask[3];
                u64 q0 = 0, q1 = 0, q2 = 0, q3 = 0;
                if (V > 1) {
                    const u64* nr = &s_mask[4];
                    q0 = nr[0]; q1 = nr[1]; q2 = nr[2]; q3 = nr[3];
                }
                for (int i = 0; i < V; ++i) {
                    u64 t0 = 0, t1 = 0, t2 = 0, t3 = 0;
                    if (i + 2 < V) {
                        const u64* nr = &s_mask[(i + 2) << 2];
                        t0 = nr[0]; t1 = nr[1]; t2 = nr[2]; t3 = nr[3];
                    }
                    int w = i >> 6;
                    u64 bit = 1ull << (i & 63);
                    u64 rw = (w == 0) ? r0 : (w == 1) ? r1 : (w == 2) ? r2 : r3;
                    if (!(rw & bit)) {
                        s_src[kept] = (unsigned short)i;
                        if (++kept >= TOPK) break;
                        r0 |= p0; r1 |= p1; r2 |= p2; r3 |= p3;
                    }
                    p0 = q0; p1 = q1; p2 = q2; p3 = q3;
                    q0 = t0; q1 = t1; q2 = t2; q3 = t3;
                }
                s_nk = kept;
            }
        } else {
            // ---- fallback (V > 256): barrier greedy ---------------------
            for (int t = tid; t < V; t += 256) s_rem[t] = 0;
            __syncthreads();
            for (int i = 0; i < V; ++i) {
                if (s_rem[i]) continue;
                if (tid == 0) {
                    int k = s_emit;
                    if (k < TOPK) s_src[k] = (unsigned short)i;
                    s_emit = k + 1;
                }
                float x1i = sx1[i], y1i = sy1[i], x2i = sx2[i], y2i = sy2[i];
                float ai  = sar[i];
                for (int jj = i + 1 + tid; jj < V; jj += 256) {
                    if (s_rem[jj]) continue;
                    float lx = fmaxf(x1i, sx1[jj]);
                    float ly = fmaxf(y1i, sy1[jj]);
                    float rx = fminf(x2i, sx2[jj]);
                    float ry = fminf(y2i, sy2[jj]);
                    float iw = fmaxf(rx - lx, 0.0f);
                    float ih = fmaxf(ry - ly, 0.0f);
                    float inter = iw * ih;
                    float iou = inter / (ai + sar[jj] - inter + 1e-9f);
                    if (iou > NMS_TH) s_rem[jj] = 1;
                }
                __syncthreads();
                if (s_emit >= TOPK) break;
            }
            if (tid == 0) s_nk = min(s_emit, TOPK);
        }
    }
    __syncthreads();

    // ---- structured TOPK output (replaces zeroing + scattered emits) ----
    const int nk = s_nk;
    if (tid < TOPK) {
        float4 bx = make_float4(0.f, 0.f, 0.f, 0.f);
        float sc = 0.f, lb = 0.f, vd = 0.f;
        if (tid < nk) {
            int s = s_src[tid];
            bx = make_float4(sx1[s], sy1[s], sx2[s], sy2[s]);
            sc = __uint_as_float((unsigned int)(s_skey[s] >> 10));
            lb = (float)col;
            vd = 1.0f;
        }
        ((float4*)out)[c * TOPK + tid] = bx;
        out[OFF_SCORES + c * TOPK + tid] = sc;
        out[OFF_LABELS + c * TOPK + tid] = lb;
        out[OFF_VALID  + c * TOPK + tid] = vd;
    }
}

extern "C" void kernel_launch(void* const* d_in, const int* in_sizes, int n_in,
                              void* d_out, int out_size, void* d_ws, size_t ws_size,
                              hipStream_t stream) {
    const float* class_logit = (const float*)d_in[0];   // [1000][81]
    const float* box_reg     = (const float*)d_in[1];   // [1000][324]
    const float* proposal    = (const float*)d_in[2];   // [1000][4]
    float* out = (float*)d_out;                         // 56000 floats

    float2* stats = (ws_size >= WS_REQUIRED) ? (float2*)d_ws : nullptr;

    if (stats) {
        stats_kernel<<<(N_PROP + 3) / 4, 256, 0, stream>>>(class_logit, stats);
    }
    nms_kernel<<<N_FG, 256, 0, stream>>>(class_logit, box_reg, proposal,
                                         stats, out);
}

// Round 7
// 82.875 us; speedup vs baseline: 1.0377x; 1.0090x over previous
//
#include <hip/hip_runtime.h>
#include <math.h>

// Problem constants (from reference)
#define N_PROP   1000
#define C_ALL    81
#define N_FG     80
#define TOPK     100
#define CAP      1024
#define IMG_WH   800.0f
#define SCORE_TH 0.05f
#define NMS_TH   0.5f
#define MIN_SZ   1.0f
#define BBOX_CLIP 4.135166556742356f   // log(1000/16)

#define NMS_BLK  512        // 8 waves: 2 waves/SIMD -> latency overlap

typedef unsigned long long u64;

// Workspace: float2 stats[1000] = 8 KB. Written every call (no stale-data
// hazard from the harness poison fill).
#define WS_REQUIRED (sizeof(float2) * N_PROP)

// ---------------------------------------------------------------- kernel 1
// Softmax stats, one wave per row (verified round-0 pattern).
__global__ __launch_bounds__(256) void stats_kernel(
    const float* __restrict__ logits,   // [1000][81]
    float2* __restrict__ stats)         // [1000] (rowmax, rowsum)
{
    const int wave = threadIdx.x >> 6;
    const int lane = threadIdx.x & 63;
    const int n = blockIdx.x * 4 + wave;
    if (n >= N_PROP) return;
    const float* row = logits + n * C_ALL;

    float v1 = row[lane];
    float v2 = (lane < C_ALL - 64) ? row[64 + lane] : 0.f;

    float m = (lane < C_ALL - 64) ? fmaxf(v1, v2) : v1;
    #pragma unroll
    for (int off = 32; off >= 1; off >>= 1)
        m = fmaxf(m, __shfl_xor(m, off, 64));

    float s = expf(v1 - m) + ((lane < C_ALL - 64) ? expf(v2 - m) : 0.0f);
    #pragma unroll
    for (int off = 32; off >= 1; off >>= 1)
        s += __shfl_xor(s, off, 64);

    if (lane == 0) stats[n] = make_float2(m, s);
}

// ---------------------------------------------------------------- kernel 2
// One block (512 thr, 8 waves) per class:
//   score 1000 rows (ILP'd gathers) -> ballot-compact candidates (~55)
//   -> decode only candidates -> rank sort -> PARALLEL bit-matrix build
//   (LDS-broadcast reads, all V<=256) -> depth-2 pipelined serial scan
//   -> structured TOPK write.
__global__ __launch_bounds__(NMS_BLK) void nms_kernel(
    const float* __restrict__ logits,   // [1000][81]
    const float* __restrict__ boxreg,   // [1000][324]
    const float* __restrict__ prop,     // [1000][4]
    const float2* __restrict__ stats,   // [1000] or nullptr (ws fallback)
    float* __restrict__ out)            // 56000 floats
{
    __shared__ float2 s_ms[N_PROP];                 // fallback-only stats
    __shared__ unsigned short s_cn[CAP];            // candidate row ids
    __shared__ float s_csc[CAP];                    // candidate scores
    __shared__ u64   s_key[CAP];                    // compacted (unsorted)
    __shared__ float cx1[CAP], cy1[CAP], cx2[CAP], cy2[CAP], car[CAP];
    __shared__ u64   s_skey[CAP];                   // sorted
    __shared__ float sx1[CAP], sy1[CAP], sx2[CAP], sy2[CAP], sar[CAP];
    __shared__ u64   s_mask[256 * 4];
    __shared__ unsigned char s_rem[CAP];
    __shared__ unsigned short s_src[TOPK];          // rank -> sorted index
    __shared__ int   s_nc, s_cnt, s_emit, s_nk;

    const int c    = blockIdx.x;
    const int tid  = threadIdx.x;
    const int lane = tid & 63;
    const int col  = c + 1;

    const int OFF_SCORES = N_FG * TOPK * 4;          // 32000
    const int OFF_LABELS = OFF_SCORES + N_FG * TOPK; // 40000
    const int OFF_VALID  = OFF_LABELS + N_FG * TOPK; // 48000

    if (tid == 0) { s_nc = 0; s_cnt = 0; s_emit = 0; s_nk = 0; }

    // ---- fallback stats (ws too small) ----------------------------------
    if (stats == nullptr) {
        for (int n = tid; n < N_PROP; n += NMS_BLK) {
            const float* row = logits + n * C_ALL;
            float m = -1e30f;
            for (int j = 0; j < C_ALL; ++j) m = fmaxf(m, row[j]);
            float s = 0.0f;
            for (int j = 0; j < C_ALL; ++j) s += expf(row[j] - m);
            s_ms[n] = make_float2(m, s);
        }
    }
    __syncthreads();

    // ---- phase B: score + threshold + ballot-compact candidates ---------
    // Both gathers + both stats loads issued up front (ILP hides latency).
    {
        const int n0 = tid;             // < 512 < 1000 always valid
        const int n1 = NMS_BLK + tid;   // valid iff < 1000
        const bool has1 = (n1 < N_PROP);

        float  l0 = logits[n0 * C_ALL + col];
        float2 m0 = stats ? stats[n0] : s_ms[n0];
        float  l1 = 0.0f;
        float2 m1 = make_float2(0.f, 1.f);
        if (has1) { l1 = logits[n1 * C_ALL + col]; m1 = stats ? stats[n1] : s_ms[n1]; }

        float sc0 = expf(l0 - m0.x) / m0.y;
        float sc1 = has1 ? (expf(l1 - m1.x) / m1.y) : 0.0f;

        bool v0 = (sc0 >= SCORE_TH);
        u64 bal = __ballot(v0);
        int pop = __popcll(bal);
        int wb = 0;
        if (lane == 0 && pop) wb = atomicAdd(&s_nc, pop);
        wb = __shfl(wb, 0, 64);
        if (v0) {
            int slot = wb + __popcll(bal & ((1ull << lane) - 1ull));
            s_cn[slot]  = (unsigned short)n0;
            s_csc[slot] = sc0;
        }

        bool v1 = has1 && (sc1 >= SCORE_TH);
        bal = __ballot(v1);
        pop = __popcll(bal);
        wb = 0;
        if (lane == 0 && pop) wb = atomicAdd(&s_nc, pop);
        wb = __shfl(wb, 0, 64);
        if (v1) {
            int slot = wb + __popcll(bal & ((1ull << lane) - 1ull));
            s_cn[slot]  = (unsigned short)n1;
            s_csc[slot] = sc1;
        }
    }
    __syncthreads();
    const int NC = s_nc;

    // ---- decode ONLY candidates -----------------------------------------
    for (int t = tid; t < NC; t += NMS_BLK) {
        int n = s_cn[t];
        float sc = s_csc[t];

        float4 p = *(const float4*)(prop + n * 4);
        float w  = p.z - p.x;
        float h  = p.w - p.y;
        float pcx0 = p.x + 0.5f * w;
        float pcy0 = p.y + 0.5f * h;

        float4 d = *(const float4*)(boxreg + n * (C_ALL * 4) + col * 4);
        float dx = d.x / 10.0f;
        float dy = d.y / 10.0f;
        float dw = fminf(d.z / 5.0f, BBOX_CLIP);
        float dh = fminf(d.w / 5.0f, BBOX_CLIP);

        float pcx = dx * w + pcx0;
        float pcy = dy * h + pcy0;
        float pw  = expf(dw) * w;
        float ph  = expf(dh) * h;

        float x1 = fminf(fmaxf(pcx - 0.5f * pw, 0.0f), IMG_WH);
        float y1 = fminf(fmaxf(pcy - 0.5f * ph, 0.0f), IMG_WH);
        float x2 = fminf(fmaxf(pcx + 0.5f * pw, 0.0f), IMG_WH);
        float y2 = fminf(fmaxf(pcy + 0.5f * ph, 0.0f), IMG_WH);

        float bw = x2 - x1;
        float bh = y2 - y1;
        if (bw >= MIN_SZ && bh >= MIN_SZ) {
            int slot = atomicAdd(&s_cnt, 1);
            // key: (score bits | 1023-n) -> descending-u64
            // == (score desc, original index asc); unique per class,
            // so compaction/append order cannot affect results.
            s_key[slot] = ((u64)__float_as_uint(sc) << 10) | (u64)(1023 - n);
            cx1[slot] = x1; cy1[slot] = y1; cx2[slot] = x2; cy2[slot] = y2;
            car[slot] = bw * bh;
        }
    }
    __syncthreads();

    const int V = s_cnt;

    if (V > 0) {
        // ---- rank sort (keys unique -> ranks unique); same-addr LDS
        //      reads across threads broadcast for free ---------------------
        for (int t = tid; t < V; t += NMS_BLK) {
            u64 myk = s_key[t];
            int rank = 0;
            #pragma unroll 4
            for (int j = 0; j < V; ++j) rank += (s_key[j] > myk) ? 1 : 0;
            s_skey[rank] = myk;
            sx1[rank] = cx1[t]; sy1[rank] = cy1[t];
            sx2[rank] = cx2[t]; sy2[rank] = cy2[t];
            sar[rank] = car[t];
        }
        __syncthreads();

        if (V <= 256) {
            // ---- PARALLEL bit-matrix build: thread handles (row i,
            //      word w).  i consecutive within a wave -> conflict-free
            //      stride-1 LDS j-streams; all 8 waves busy. --------------
            for (int i0 = 0; i0 < V; i0 += 128) {
                int i = i0 + (tid & 127);
                int w = tid >> 7;               // 0..3
                if (i < V) {
                    float x1i = sx1[i], y1i = sy1[i];
                    float x2i = sx2[i], y2i = sy2[i];
                    float ai  = sar[i];
                    u64 mrow = 0;
                    int j0 = w << 6;
                    int j1 = min(V, j0 + 64);
                    for (int j = max(j0, i + 1); j < j1; ++j) {
                        float lx = fmaxf(x1i, sx1[j]);
                        float ly = fmaxf(y1i, sy1[j]);
                        float rx = fminf(x2i, sx2[j]);
                        float ry = fminf(y2i, sy2[j]);
                        float iw = fmaxf(rx - lx, 0.0f);
                        float ih = fmaxf(ry - ly, 0.0f);
                        float inter = iw * ih;
                        float iou = inter / (ai + sar[j] - inter + 1e-9f);
                        if (iou > NMS_TH) mrow |= 1ull << (j - j0);
                    }
                    s_mask[(i << 2) + w] = mrow;   // all 4 words written
                }
            }
            __syncthreads();

            if (tid == 0) {
                // Serial greedy scan, depth-2 software pipeline; records
                // s_src[rank] directly.
                u64 r0 = 0, r1 = 0, r2 = 0, r3 = 0;
                int kept = 0;
                u64 p0 = s_mask[0], p1 = s_mask[1], p2 = s_mask[2], p3 = s_mask[3];
                u64 q0 = 0, q1 = 0, q2 = 0, q3 = 0;
                if (V > 1) {
                    const u64* nr = &s_mask[4];
                    q0 = nr[0]; q1 = nr[1]; q2 = nr[2]; q3 = nr[3];
                }
                for (int i = 0; i < V; ++i) {
                    u64 t0 = 0, t1 = 0, t2 = 0, t3 = 0;
                    if (i + 2 < V) {
                        const u64* nr = &s_mask[(i + 2) << 2];
                        t0 = nr[0]; t1 = nr[1]; t2 = nr[2]; t3 = nr[3];
                    }
                    int w = i >> 6;
                    u64 bit = 1ull << (i & 63);
                    u64 rw = (w == 0) ? r0 : (w == 1) ? r1 : (w == 2) ? r2 : r3;
                    if (!(rw & bit)) {
                        s_src[kept] = (unsigned short)i;
                        if (++kept >= TOPK) break;
                        r0 |= p0; r1 |= p1; r2 |= p2; r3 |= p3;
                    }
                    p0 = q0; p1 = q1; p2 = q2; p3 = q3;
                    q0 = t0; q1 = t1; q2 = t2; q3 = t3;
                }
                s_nk = kept;
            }
        } else {
            // ---- fallback (V > 256): barrier greedy ---------------------
            for (int t = tid; t < V; t += NMS_BLK) s_rem[t] = 0;
            __syncthreads();
            for (int i = 0; i < V; ++i) {
                if (s_rem[i]) continue;
                if (tid == 0) {
                    int k = s_emit;
                    if (k < TOPK) s_src[k] = (unsigned short)i;
                    s_emit = k + 1;
                }
                float x1i = sx1[i], y1i = sy1[i], x2i = sx2[i], y2i = sy2[i];
                float ai  = sar[i];
                for (int jj = i + 1 + tid; jj < V; jj += NMS_BLK) {
                    if (s_rem[jj]) continue;
                    float lx = fmaxf(x1i, sx1[jj]);
                    float ly = fmaxf(y1i, sy1[jj]);
                    float rx = fminf(x2i, sx2[jj]);
                    float ry = fminf(y2i, sy2[jj]);
                    float iw = fmaxf(rx - lx, 0.0f);
                    float ih = fmaxf(ry - ly, 0.0f);
                    float inter = iw * ih;
                    float iou = inter / (ai + sar[jj] - inter + 1e-9f);
                    if (iou > NMS_TH) s_rem[jj] = 1;
                }
                __syncthreads();
                if (s_emit >= TOPK) break;
            }
            if (tid == 0) s_nk = min(s_emit, TOPK);
        }
    }
    __syncthreads();

    // ---- structured TOPK output (no separate zeroing pass) --------------
    const int nk = s_nk;
    if (tid < TOPK) {
        float4 bx = make_float4(0.f, 0.f, 0.f, 0.f);
        float sc = 0.f, lb = 0.f, vd = 0.f;
        if (tid < nk) {
            int s = s_src[tid];
            bx = make_float4(sx1[s], sy1[s], sx2[s], sy2[s]);
            sc = __uint_as_float((unsigned int)(s_skey[s] >> 10));
            lb = (float)col;
            vd = 1.0f;
        }
        ((float4*)out)[c * TOPK + tid] = bx;
        out[OFF_SCORES + c * TOPK + tid] = sc;
        out[OFF_LABELS + c * TOPK + tid] = lb;
        out[OFF_VALID  + c * TOPK + tid] = vd;
    }
}

extern "C" void kernel_launch(void* const* d_in, const int* in_sizes, int n_in,
                              void* d_out, int out_size, void* d_ws, size_t ws_size,
                              hipStream_t stream) {
    const float* class_logit = (const float*)d_in[0];   // [1000][81]
    const float* box_reg     = (const float*)d_in[1];   // [1000][324]
    const float* proposal    = (const float*)d_in[2];   // [1000][4]
    float* out = (float*)d_out;                         // 56000 floats

    float2* stats = (ws_size >= WS_REQUIRED) ? (float2*)d_ws : nullptr;

    if (stats) {
        stats_kernel<<<(N_PROP + 3) / 4, 256, 0, stream>>>(class_logit, stats);
    }
    nms_kernel<<<N_FG, NMS_BLK, 0, stream>>>(class_logit, box_reg, proposal,
                                             stats, out);
}